// Round 1
// baseline (487.524 us; speedup 1.0000x reference)
//
#include <hip/hip_runtime.h>
#include <math.h>

#define L_SIG 160000
#define N_FFTC 512
#define HOPC 128
#define FD 257
#define TDIM 1251          // (160512 - 512)/128 + 1
#define ROW 4112           // 16 * 257
#define NBC 64             // B*C

// ws layout (floats): [0:512) hann | [512:1024) twiddle (256 x float2) |
// [1024:2052) sv_re[c][f] | [2052:3080) sv_im[c][f]

__global__ __launch_bounds__(512) void setup_kernel(const float* __restrict__ angle,
                                                    const float* __restrict__ mic,
                                                    float* __restrict__ tbl) {
    int tid = threadIdx.x;
    const float TWO_PI = 6.2831853071795864769f;
    // Hann window: 0.5*(1 - cos(2*pi*i/512))
    if (tid < 512) {
        tbl[tid] = 0.5f * (1.0f - cosf(TWO_PI * (float)tid / 512.0f));
    }
    // Twiddles T[j] = exp(-2*pi*i*j/512), j in [0,256)
    if (tid < 256) {
        float th = -TWO_PI * (float)tid / 512.0f;
        tbl[512 + 2 * tid]     = cosf(th);
        tbl[512 + 2 * tid + 1] = sinf(th);
    }
    __shared__ float tdoa[4];
    if (tid == 0) {
        const float half_pi = (float)(M_PI / 2.0);
        float s90 = sinf(half_pi);
        float c90 = cosf(half_pi);
        float acc0 = 0.f, acc1 = 0.f, acc2 = 0.f, acc3 = 0.f;
        for (int b = 0; b < 16; ++b) {
            float ang = angle[b];
            float rad = -ang * (float)(M_PI / 180.0);
            float lx = cosf(rad) * s90;
            float ly = sinf(rad) * s90;
            float lz = c90;                 // DIST = 1.0
            #pragma unroll
            for (int c = 0; c < 4; ++c) {
                const float* m = mic + ((size_t)b * 4 + c) * 3;
                float dx = m[0] - lx, dy = m[1] - ly, dz = m[2] - lz;
                float s = dx * dx + dy * dy + dz * dz;
                if (c == 0) acc0 += s;
                else if (c == 1) acc1 += s;
                else if (c == 2) acc2 += s;
                else acc3 += s;
            }
        }
        float t0 = sqrtf(acc0);
        tdoa[0] = 0.0f;
        tdoa[1] = sqrtf(acc1) - t0;
        tdoa[2] = sqrtf(acc2) - t0;
        tdoa[3] = sqrtf(acc3) - t0;
    }
    __syncthreads();
    const float coef = (float)(-2.0 * M_PI * 16000.0 / (512.0 * 340.4));
    for (int i = tid; i < 4 * FD; i += 512) {
        int c = i / FD;
        int f = i - c * FD;
        float ph = coef * (float)f * tdoa[c];
        tbl[1024 + i] = cosf(ph) * 0.5f;   // / sqrt(C)=2
        tbl[2052 + i] = sinf(ph) * 0.5f;
    }
}

__global__ __launch_bounds__(256) void stft_kernel(const float* __restrict__ x,
                                                   const float* __restrict__ tbl,
                                                   float* __restrict__ out) {
    __shared__ float2 bufA[512];
    __shared__ float2 bufB[512];
    __shared__ float2 tw[256];
    int tid = threadIdx.x;
    int bid = blockIdx.x;
    int t  = bid % TDIM;
    int bc = bid / TDIM;          // 0..63
    int b  = bc >> 2;
    int c  = bc & 3;

    const float* xs = x + (size_t)bc * L_SIG;

    // stage twiddles to LDS
    tw[tid] = ((const float2*)(tbl + 512))[tid];

    // load + reflect pad + window
    for (int i = tid; i < 512; i += 256) {
        int g = t * HOPC - 256 + i;
        if (g < 0) g = -g;
        if (g >= L_SIG) g = 2 * L_SIG - 2 - g;
        float v = xs[g] * tbl[i];
        bufA[i] = make_float2(v, 0.0f);
    }
    __syncthreads();

    // 9-stage Stockham radix-2 FFT (DIF), ping-pong A->B->A->...->B
    float2* src = bufA;
    float2* dst = bufB;
    #pragma unroll
    for (int s = 0; s < 9; ++s) {
        int m  = 1 << s;
        int lo = tid & (m - 1);
        int hi = tid ^ lo;            // tid & ~(m-1)
        float2 a  = src[tid];
        float2 b2 = src[tid + 256];
        float2 w  = tw[hi];
        float2 sum = make_float2(a.x + b2.x, a.y + b2.y);
        float2 dif = make_float2(a.x - b2.x, a.y - b2.y);
        float2 dw  = make_float2(dif.x * w.x - dif.y * w.y,
                                 dif.x * w.y + dif.y * w.x);
        dst[2 * hi + lo]     = sum;
        dst[2 * hi + lo + m] = dw;
        __syncthreads();
        float2* tmp = src; src = dst; dst = tmp;
    }
    // result now in src (9 swaps: ends in bufB)

    size_t base = ((size_t)b * TDIM + t) * ROW + (size_t)c * FD;
    const float* svre = tbl + 1024 + c * FD;
    const float* svim = tbl + 2052 + c * FD;
    for (int f = tid; f < FD; f += 256) {
        float2 X = src[f];
        out[base + f]            = X.x;       // X.real   (ch = c)
        out[base + 1028 + f]     = X.y;       // X.imag   (ch = 4+c)
        out[base + 2056 + f]     = svre[f];   // sv.real  (ch = 8+c)
        out[base + 3084 + f]     = svim[f];   // sv.imag  (ch = 12+c)
    }
}

extern "C" void kernel_launch(void* const* d_in, const int* in_sizes, int n_in,
                              void* d_out, int out_size, void* d_ws, size_t ws_size,
                              hipStream_t stream) {
    const float* x     = (const float*)d_in[0];
    const float* angle = (const float*)d_in[1];
    const float* mic   = (const float*)d_in[2];
    float* out = (float*)d_out;
    float* tbl = (float*)d_ws;

    setup_kernel<<<1, 512, 0, stream>>>(angle, mic, tbl);
    stft_kernel<<<NBC * TDIM, 256, 0, stream>>>(x, tbl, out);
}

// Round 2
// 461.892 us; speedup vs baseline: 1.0555x; 1.0555x over previous
//
#include <hip/hip_runtime.h>
#include <math.h>

#define L_SIG 160000
#define HOPC 128
#define FD 257
#define TDIM 1251          // (160512 - 512)/128 + 1
#define ROW 4112           // 16 * 257
#define NBC 64             // B*C
#define NFR (NBC * TDIM)   // 80064 frames (even)
#define NPAIR (NFR / 2)    // 40032 wave-pairs

// ws layout (floats): [1024:2052) sv_re[c][f] | [2052:3080) sv_im[c][f]

__global__ __launch_bounds__(256) void setup_kernel(const float* __restrict__ angle,
                                                    const float* __restrict__ mic,
                                                    float* __restrict__ tbl) {
    int tid = threadIdx.x;
    __shared__ float tdoa[4];
    if (tid == 0) {
        const float half_pi = (float)(M_PI / 2.0);
        float s90 = sinf(half_pi);
        float c90 = cosf(half_pi);
        float acc0 = 0.f, acc1 = 0.f, acc2 = 0.f, acc3 = 0.f;
        for (int b = 0; b < 16; ++b) {
            float ang = angle[b];
            float rad = -ang * (float)(M_PI / 180.0);
            float lx = cosf(rad) * s90;
            float ly = sinf(rad) * s90;
            float lz = c90;                 // DIST = 1.0
            #pragma unroll
            for (int c = 0; c < 4; ++c) {
                const float* m = mic + ((size_t)b * 4 + c) * 3;
                float dx = m[0] - lx, dy = m[1] - ly, dz = m[2] - lz;
                float s = dx * dx + dy * dy + dz * dz;
                if (c == 0) acc0 += s; else if (c == 1) acc1 += s;
                else if (c == 2) acc2 += s; else acc3 += s;
            }
        }
        float t0 = sqrtf(acc0);
        tdoa[0] = 0.0f;
        tdoa[1] = sqrtf(acc1) - t0;
        tdoa[2] = sqrtf(acc2) - t0;
        tdoa[3] = sqrtf(acc3) - t0;
    }
    __syncthreads();
    const float coef = (float)(-2.0 * M_PI * 16000.0 / (512.0 * 340.4));
    for (int i = tid; i < 4 * FD; i += 256) {
        int c = i / FD;
        int f = i - c * FD;
        float ph = coef * (float)f * tdoa[c];
        tbl[1024 + i] = cosf(ph) * 0.5f;   // / ||sv|| = sqrt(C) = 2
        tbl[2052 + i] = sinf(ph) * 0.5f;
    }
}

// 8-point complex DFT in registers (DIF split): z_k = sum_r z_r * W8^{kr}
__device__ __forceinline__ void bfly8(float (&zr)[8], float (&zi)[8]) {
    const float C = 0.70710678118654752440f;   // sqrt(2)/2
    float sr0=zr[0]+zr[4], si0=zi[0]+zi[4], dr0=zr[0]-zr[4], di0=zi[0]-zi[4];
    float sr1=zr[1]+zr[5], si1=zi[1]+zi[5], dr1=zr[1]-zr[5], di1=zi[1]-zi[5];
    float sr2=zr[2]+zr[6], si2=zi[2]+zi[6], dr2=zr[2]-zr[6], di2=zi[2]-zi[6];
    float sr3=zr[3]+zr[7], si3=zi[3]+zi[7], dr3=zr[3]-zr[7], di3=zi[3]-zi[7];
    // d1 *= C(1-i); d2 *= -i; d3 *= C(-1-i)
    float t;
    t = C*(dr1+di1); di1 = C*(di1-dr1); dr1 = t;
    t = dr2; dr2 = di2; di2 = -t;
    t = C*(di3-dr3); di3 = -C*(dr3+di3); dr3 = t;
    // even outputs: 4pt DFT of s
    float p0r=sr0+sr2, p0i=si0+si2, p1r=sr1+sr3, p1i=si1+si3;
    float q0r=sr0-sr2, q0i=si0-si2, q1r=sr1-sr3, q1i=si1-si3;
    zr[0]=p0r+p1r; zi[0]=p0i+p1i;
    zr[2]=q0r+q1i; zi[2]=q0i-q1r;   // B1 = q0 - i*q1
    zr[4]=p0r-p1r; zi[4]=p0i-p1i;
    zr[6]=q0r-q1i; zi[6]=q0i+q1r;   // B3 = q0 + i*q1
    // odd outputs: 4pt DFT of d
    p0r=dr0+dr2; p0i=di0+di2; p1r=dr1+dr3; p1i=di1+di3;
    q0r=dr0-dr2; q0i=di0-di2; q1r=dr1-dr3; q1i=di1-di3;
    zr[1]=p0r+p1r; zi[1]=p0i+p1i;
    zr[3]=q0r+q1i; zi[3]=q0i-q1r;
    zr[5]=p0r-p1r; zi[5]=p0i-p1i;
    zr[7]=q0r-q1i; zi[7]=q0i+q1r;
}

// z_k *= w^k for k=1..7 (w = (wr,wi)), powers by iterated complex mult
__device__ __forceinline__ void twiddle8(float (&zr)[8], float (&zi)[8], float wr, float wi) {
    float pr = wr, pi = wi;
    #pragma unroll
    for (int k = 1; k < 8; ++k) {
        float tr = zr[k]*pr - zi[k]*pi;
        zi[k]    = zr[k]*pi + zi[k]*pr;
        zr[k]    = tr;
        if (k < 7) { float n = pr*wr - pi*wi; pi = pr*wi + pi*wr; pr = n; }
    }
}

#define PHYS(i) ((i) + ((i) >> 3))   // LDS pad: +1 float2 per 8

__global__ __launch_bounds__(256) void stft8_kernel(const float* __restrict__ x,
                                                    const float* __restrict__ tbl,
                                                    float* __restrict__ out) {
    __shared__ float2 exch[4][576];   // 512 + 64 pad per wave
    const int tid = threadIdx.x;
    const int wv  = tid >> 6;
    const int j   = tid & 63;
    const int pid = blockIdx.x * 4 + wv;
    const int fid0 = 2 * pid;
    const int fid1 = fid0 + 1;
    const int t0 = fid0 % TDIM, bc0 = fid0 / TDIM;
    const int t1 = fid1 % TDIM, bc1 = fid1 / TDIM;

    // window factors: hann[j+64r] = 0.5 - 0.5*cos(theta + r*pi/4), theta = pi*j/256
    const float PI_256 = 0.012271846303085129838f;   // pi/256
    float sj, cj;
    __sincosf((float)j * PI_256, &sj, &cj);
    const float R2 = 0.70710678118654752440f;
    float cv[8];
    cv[0] = cj;            cv[1] = (cj - sj) * R2;
    cv[2] = -sj;           cv[3] = (-cj - sj) * R2;
    cv[4] = -cj;           cv[5] = (sj - cj) * R2;
    cv[6] = sj;            cv[7] = (cj + sj) * R2;

    // packed load: frame0 -> real, frame1 -> imag (reflect pad + window)
    const float* xs0 = x + (size_t)bc0 * L_SIG;
    const float* xs1 = x + (size_t)bc1 * L_SIG;
    const int g0 = t0 * HOPC - 256 + j;
    const int g1 = t1 * HOPC - 256 + j;
    float zr[8], zi[8];
    #pragma unroll
    for (int r = 0; r < 8; ++r) {
        int a0 = g0 + 64 * r; a0 = (a0 < 0) ? -a0 : a0; if (a0 >= L_SIG) a0 = 2 * L_SIG - 2 - a0;
        int a1 = g1 + 64 * r; a1 = (a1 < 0) ? -a1 : a1; if (a1 >= L_SIG) a1 = 2 * L_SIG - 2 - a1;
        float w = 0.5f - 0.5f * cv[r];
        zr[r] = xs0[a0] * w;
        zi[r] = xs1[a1] * w;
    }

    float2* buf = exch[wv];

    // ---- stage 0 (m=1, hi=j): butterfly, twiddle w=e^{-2pi i j/512}=(cj,-sj), write 8j+k
    bfly8(zr, zi);
    twiddle8(zr, zi, cj, -sj);
    #pragma unroll
    for (int k = 0; k < 8; ++k) {
        int idx = 8 * j + k;
        buf[PHYS(idx)] = make_float2(zr[k], zi[k]);   // phys = 9j+k, contiguous
    }
    __syncthreads();
    #pragma unroll
    for (int r = 0; r < 8; ++r) {
        int idx = j + 64 * r;
        float2 v = buf[PHYS(idx)];
        zr[r] = v.x; zi[r] = v.y;
    }

    // ---- stage 1 (m=8, hi=j&~7): butterfly, twiddle, write 64*(j>>3)+(j&7)+8k
    bfly8(zr, zi);
    float s1v, c1v;
    __sincosf((float)(j & ~7) * PI_256, &s1v, &c1v);
    twiddle8(zr, zi, c1v, -s1v);
    __syncthreads();   // guard WAR across nothing cross-wave; cheap alignment barrier
    #pragma unroll
    for (int k = 0; k < 8; ++k) {
        int idx = 64 * (j >> 3) + (j & 7) + 8 * k;
        buf[PHYS(idx)] = make_float2(zr[k], zi[k]);
    }
    __syncthreads();
    #pragma unroll
    for (int r = 0; r < 8; ++r) {
        int idx = j + 64 * r;
        float2 v = buf[PHYS(idx)];
        zr[r] = v.x; zi[r] = v.y;
    }

    // ---- stage 2 (m=64, hi=0): butterfly only -> Z[j + 64k] in (zr[k], zi[k])
    bfly8(zr, zi);

    // conj partner Z[(512-f)&511]: lane (64-j)&63, reg 7-k (j>=1) or (8-k)&7 (j==0)
    const int srcl = (64 - j) & 63;
    float pr_[8], pi_[8];
    #pragma unroll
    for (int m = 0; m < 8; ++m) {
        pr_[m] = __shfl(zr[m], srcl, 64);
        pi_[m] = __shfl(zi[m], srcl, 64);
    }

    const int b0 = bc0 >> 2, c0 = bc0 & 3;
    const int b1 = bc1 >> 2, c1 = bc1 & 3;
    const size_t base0 = ((size_t)b0 * TDIM + t0) * ROW + (size_t)c0 * FD;
    const size_t base1 = ((size_t)b1 * TDIM + t1) * ROW + (size_t)c1 * FD;
    const float* sv0r = tbl + 1024 + c0 * FD;
    const float* sv0i = tbl + 2052 + c0 * FD;
    const float* sv1r = tbl + 1024 + c1 * FD;
    const float* sv1i = tbl + 2052 + c1 * FD;
    const bool l0 = (j == 0);

    #pragma unroll
    for (int k = 0; k < 5; ++k) {
        float Pr = l0 ? pr_[(8 - k) & 7] : pr_[7 - k];
        float Pi = l0 ? pi_[(8 - k) & 7] : pi_[7 - k];
        // F0 = (Z + conj(P))/2 ; F1 = -i(Z - conj(P))/2
        float F0r = 0.5f * (zr[k] + Pr);
        float F0i = 0.5f * (zi[k] - Pi);
        float F1r = 0.5f * (zi[k] + Pi);
        float F1i = 0.5f * (Pr - zr[k]);
        int f = j + 64 * k;
        if (k < 4 || l0) {          // f <= 256
            __builtin_nontemporal_store(F0r,     out + base0 + f);
            __builtin_nontemporal_store(F0i,     out + base0 + 1028 + f);
            __builtin_nontemporal_store(sv0r[f], out + base0 + 2056 + f);
            __builtin_nontemporal_store(sv0i[f], out + base0 + 3084 + f);
            __builtin_nontemporal_store(F1r,     out + base1 + f);
            __builtin_nontemporal_store(F1i,     out + base1 + 1028 + f);
            __builtin_nontemporal_store(sv1r[f], out + base1 + 2056 + f);
            __builtin_nontemporal_store(sv1i[f], out + base1 + 3084 + f);
        }
    }
}

extern "C" void kernel_launch(void* const* d_in, const int* in_sizes, int n_in,
                              void* d_out, int out_size, void* d_ws, size_t ws_size,
                              hipStream_t stream) {
    const float* x     = (const float*)d_in[0];
    const float* angle = (const float*)d_in[1];
    const float* mic   = (const float*)d_in[2];
    float* out = (float*)d_out;
    float* tbl = (float*)d_ws;

    setup_kernel<<<1, 256, 0, stream>>>(angle, mic, tbl);
    stft8_kernel<<<NPAIR / 4, 256, 0, stream>>>(x, tbl, out);
}

// Round 4
// 459.001 us; speedup vs baseline: 1.0621x; 1.0063x over previous
//
#include <hip/hip_runtime.h>
#include <math.h>

#define L_SIG 160000
#define HOPC 128
#define FD 257
#define TDIM 1251          // (160512 - 512)/128 + 1
#define ROW 4112           // 16 * 257
#define NROWS (16 * TDIM)  // 20016 output rows
#define NBC 64             // B*C
#define NFR (NBC * TDIM)   // 80064 frames (even)
#define NPAIR (NFR / 2)    // 40032 wave-pairs

typedef float floatx4 __attribute__((ext_vector_type(4)));

// ws layout (floats): [0:2056) sv row-suffix S = [svre c=0..3 (257 each), svim c=0..3]

__global__ __launch_bounds__(256) void setup_kernel(const float* __restrict__ angle,
                                                    const float* __restrict__ mic,
                                                    float* __restrict__ tbl) {
    int tid = threadIdx.x;
    __shared__ float tdoa[4];
    if (tid == 0) {
        const float half_pi = (float)(M_PI / 2.0);
        float s90 = sinf(half_pi);
        float c90 = cosf(half_pi);
        float acc0 = 0.f, acc1 = 0.f, acc2 = 0.f, acc3 = 0.f;
        for (int b = 0; b < 16; ++b) {
            float ang = angle[b];
            float rad = -ang * (float)(M_PI / 180.0);
            float lx = cosf(rad) * s90;
            float ly = sinf(rad) * s90;
            float lz = c90;                 // DIST = 1.0
            #pragma unroll
            for (int c = 0; c < 4; ++c) {
                const float* m = mic + ((size_t)b * 4 + c) * 3;
                float dx = m[0] - lx, dy = m[1] - ly, dz = m[2] - lz;
                float s = dx * dx + dy * dy + dz * dz;
                if (c == 0) acc0 += s; else if (c == 1) acc1 += s;
                else if (c == 2) acc2 += s; else acc3 += s;
            }
        }
        float t0 = sqrtf(acc0);
        tdoa[0] = 0.0f;
        tdoa[1] = sqrtf(acc1) - t0;
        tdoa[2] = sqrtf(acc2) - t0;
        tdoa[3] = sqrtf(acc3) - t0;
    }
    __syncthreads();
    const float coef = (float)(-2.0 * M_PI * 16000.0 / (512.0 * 340.4));
    for (int i = tid; i < 4 * FD; i += 256) {
        int c = i / FD;
        int f = i - c * FD;
        float ph = coef * (float)f * tdoa[c];
        tbl[i]        = cosf(ph) * 0.5f;   // sv.re, / ||sv|| = sqrt(C) = 2
        tbl[1028 + i] = sinf(ph) * 0.5f;   // sv.im
    }
}

// Broadcast the fixed 2056-float sv suffix to every output row (channels 8..15).
__global__ __launch_bounds__(512) void sv_bcast(const float* __restrict__ tbl,
                                                float* __restrict__ out) {
    const int row = blockIdx.x;
    const int tid = threadIdx.x;
    const floatx4* S4 = (const floatx4*)tbl;        // 514 float4s
    floatx4* dst = (floatx4*)(out + (size_t)row * ROW + 2056);
    floatx4 v0 = S4[tid];
    __builtin_nontemporal_store(v0, dst + tid);
    if (tid < 2) {
        floatx4 v1 = S4[512 + tid];
        __builtin_nontemporal_store(v1, dst + 512 + tid);
    }
}

// 8-point complex DFT in registers (DIF split)
__device__ __forceinline__ void bfly8(float (&zr)[8], float (&zi)[8]) {
    const float C = 0.70710678118654752440f;   // sqrt(2)/2
    float sr0=zr[0]+zr[4], si0=zi[0]+zi[4], dr0=zr[0]-zr[4], di0=zi[0]-zi[4];
    float sr1=zr[1]+zr[5], si1=zi[1]+zi[5], dr1=zr[1]-zr[5], di1=zi[1]-zi[5];
    float sr2=zr[2]+zr[6], si2=zi[2]+zi[6], dr2=zr[2]-zr[6], di2=zi[2]-zi[6];
    float sr3=zr[3]+zr[7], si3=zi[3]+zi[7], dr3=zr[3]-zr[7], di3=zi[3]-zi[7];
    float t;
    t = C*(dr1+di1); di1 = C*(di1-dr1); dr1 = t;
    t = dr2; dr2 = di2; di2 = -t;
    t = C*(di3-dr3); di3 = -C*(dr3+di3); dr3 = t;
    float p0r=sr0+sr2, p0i=si0+si2, p1r=sr1+sr3, p1i=si1+si3;
    float q0r=sr0-sr2, q0i=si0-si2, q1r=sr1-sr3, q1i=si1-si3;
    zr[0]=p0r+p1r; zi[0]=p0i+p1i;
    zr[2]=q0r+q1i; zi[2]=q0i-q1r;
    zr[4]=p0r-p1r; zi[4]=p0i-p1i;
    zr[6]=q0r-q1i; zi[6]=q0i+q1r;
    p0r=dr0+dr2; p0i=di0+di2; p1r=dr1+dr3; p1i=di1+di3;
    q0r=dr0-dr2; q0i=di0-di2; q1r=dr1-dr3; q1i=di1-di3;
    zr[1]=p0r+p1r; zi[1]=p0i+p1i;
    zr[3]=q0r+q1i; zi[3]=q0i-q1r;
    zr[5]=p0r-p1r; zi[5]=p0i-p1i;
    zr[7]=q0r-q1i; zi[7]=q0i+q1r;
}

__device__ __forceinline__ void cmul(float& r, float& i, float ar, float ai, float br, float bi) {
    r = ar * br - ai * bi;
    i = ar * bi + ai * br;
}

// z_k *= w^k, k=1..7, tree-structured powers (dep depth 3)
__device__ __forceinline__ void twiddle8(float (&zr)[8], float (&zi)[8], float wr, float wi) {
    float p2r, p2i, p3r, p3i, p4r, p4i, p5r, p5i, p6r, p6i, p7r, p7i;
    cmul(p2r, p2i, wr, wi, wr, wi);
    cmul(p3r, p3i, p2r, p2i, wr, wi);
    cmul(p4r, p4i, p2r, p2i, p2r, p2i);
    cmul(p5r, p5i, p4r, p4i, wr, wi);
    cmul(p6r, p6i, p3r, p3i, p3r, p3i);
    cmul(p7r, p7i, p4r, p4i, p3r, p3i);
    float t;
    t = zr[1]*wr - zi[1]*wi;  zi[1] = zr[1]*wi + zi[1]*wr;  zr[1] = t;
    t = zr[2]*p2r - zi[2]*p2i; zi[2] = zr[2]*p2i + zi[2]*p2r; zr[2] = t;
    t = zr[3]*p3r - zi[3]*p3i; zi[3] = zr[3]*p3i + zi[3]*p3r; zr[3] = t;
    t = zr[4]*p4r - zi[4]*p4i; zi[4] = zr[4]*p4i + zi[4]*p4r; zr[4] = t;
    t = zr[5]*p5r - zi[5]*p5i; zi[5] = zr[5]*p5i + zi[5]*p5r; zr[5] = t;
    t = zr[6]*p6r - zi[6]*p6i; zi[6] = zr[6]*p6i + zi[6]*p6r; zr[6] = t;
    t = zr[7]*p7r - zi[7]*p7i; zi[7] = zr[7]*p7i + zi[7]*p7r; zr[7] = t;
}

#define PHYS(i) ((i) + ((i) >> 3))   // LDS pad: +1 float2 per 8

// One wave = 2 packed real frames -> one complex 512-FFT. No block barriers:
// each wave owns its own LDS slice; in-wave DS ordering is program order.
__global__ __launch_bounds__(256) void stft8_kernel(const float* __restrict__ x,
                                                    float* __restrict__ out) {
    __shared__ float2 exch[4][576];
    const int tid = threadIdx.x;
    const int wv  = tid >> 6;
    const int j   = tid & 63;
    const int pid = blockIdx.x * 4 + wv;
    const int fid0 = 2 * pid;
    const int fid1 = fid0 + 1;
    const int t0 = fid0 % TDIM, bc0 = fid0 / TDIM;
    const int t1 = fid1 % TDIM, bc1 = fid1 / TDIM;

    // hann[j+64r] = 0.5 - 0.5*cos(theta + r*pi/4), theta = pi*j/256
    const float PI_256 = 0.012271846303085129838f;
    float sj, cj;
    __sincosf((float)j * PI_256, &sj, &cj);
    const float R2 = 0.70710678118654752440f;
    float cv[8];
    cv[0] = cj;            cv[1] = (cj - sj) * R2;
    cv[2] = -sj;           cv[3] = (-cj - sj) * R2;
    cv[4] = -cj;           cv[5] = (sj - cj) * R2;
    cv[6] = sj;            cv[7] = (cj + sj) * R2;

    const float* xs0 = x + (size_t)bc0 * L_SIG;
    const float* xs1 = x + (size_t)bc1 * L_SIG;
    const int g0 = t0 * HOPC - 256 + j;
    const int g1 = t1 * HOPC - 256 + j;
    float zr[8], zi[8];
    #pragma unroll
    for (int r = 0; r < 8; ++r) {
        int a0 = g0 + 64 * r; a0 = (a0 < 0) ? -a0 : a0; if (a0 >= L_SIG) a0 = 2 * L_SIG - 2 - a0;
        int a1 = g1 + 64 * r; a1 = (a1 < 0) ? -a1 : a1; if (a1 >= L_SIG) a1 = 2 * L_SIG - 2 - a1;
        float w = 0.5f - 0.5f * cv[r];
        zr[r] = xs0[a0] * w;
        zi[r] = xs1[a1] * w;
    }

    float2* buf = exch[wv];

    // stage 0 (m=1): w = e^{-2pi i j/512} = (cj, -sj)
    bfly8(zr, zi);
    twiddle8(zr, zi, cj, -sj);
    #pragma unroll
    for (int k = 0; k < 8; ++k) {
        int idx = 8 * j + k;
        buf[PHYS(idx)] = make_float2(zr[k], zi[k]);
    }
    #pragma unroll
    for (int r = 0; r < 8; ++r) {
        int idx = j + 64 * r;
        float2 v = buf[PHYS(idx)];
        zr[r] = v.x; zi[r] = v.y;
    }

    // stage 1 (m=8): w = e^{-2pi i (j&~7)/512}
    bfly8(zr, zi);
    float s1v, c1v;
    __sincosf((float)(j & ~7) * PI_256, &s1v, &c1v);
    twiddle8(zr, zi, c1v, -s1v);
    #pragma unroll
    for (int k = 0; k < 8; ++k) {
        int idx = 64 * (j >> 3) + (j & 7) + 8 * k;
        buf[PHYS(idx)] = make_float2(zr[k], zi[k]);
    }
    #pragma unroll
    for (int r = 0; r < 8; ++r) {
        int idx = j + 64 * r;
        float2 v = buf[PHYS(idx)];
        zr[r] = v.x; zi[r] = v.y;
    }

    // stage 2 (m=64): butterfly only -> Z[j + 64k]
    bfly8(zr, zi);

    // conj partner Z[(512-f)&511]: lane (64-j)&63, reg 7-k (j>=1) or (8-k)&7 (j==0)
    const int srcl = (64 - j) & 63;
    float pr_[8], pi_[8];
    #pragma unroll
    for (int m = 0; m < 8; ++m) {
        pr_[m] = __shfl(zr[m], srcl, 64);
        pi_[m] = __shfl(zi[m], srcl, 64);
    }

    const int b0 = bc0 >> 2, c0 = bc0 & 3;
    const int b1 = bc1 >> 2, c1 = bc1 & 3;
    const size_t base0 = ((size_t)b0 * TDIM + t0) * ROW + (size_t)c0 * FD;
    const size_t base1 = ((size_t)b1 * TDIM + t1) * ROW + (size_t)c1 * FD;
    const bool l0 = (j == 0);

    #pragma unroll
    for (int k = 0; k < 5; ++k) {
        float Pr = l0 ? pr_[(8 - k) & 7] : pr_[7 - k];
        float Pi = l0 ? pi_[(8 - k) & 7] : pi_[7 - k];
        // F0 = (Z + conj(P))/2 ; F1 = -i(Z - conj(P))/2
        float F0r = 0.5f * (zr[k] + Pr);
        float F0i = 0.5f * (zi[k] - Pi);
        float F1r = 0.5f * (zi[k] + Pi);
        float F1i = 0.5f * (Pr - zr[k]);
        int f = j + 64 * k;
        if (k < 4 || l0) {          // f <= 256
            __builtin_nontemporal_store(F0r, out + base0 + f);
            __builtin_nontemporal_store(F0i, out + base0 + 1028 + f);
            __builtin_nontemporal_store(F1r, out + base1 + f);
            __builtin_nontemporal_store(F1i, out + base1 + 1028 + f);
        }
    }
}

extern "C" void kernel_launch(void* const* d_in, const int* in_sizes, int n_in,
                              void* d_out, int out_size, void* d_ws, size_t ws_size,
                              hipStream_t stream) {
    const float* x     = (const float*)d_in[0];
    const float* angle = (const float*)d_in[1];
    const float* mic   = (const float*)d_in[2];
    float* out = (float*)d_out;
    float* tbl = (float*)d_ws;

    setup_kernel<<<1, 256, 0, stream>>>(angle, mic, tbl);
    stft8_kernel<<<NPAIR / 4, 256, 0, stream>>>(x, out);
    sv_bcast<<<NROWS, 512, 0, stream>>>(tbl, out);
}